// Round 7
// baseline (258.570 us; speedup 1.0000x reference)
//
#include <hip/hip_runtime.h>

// KNN argmin over L2, round 7: phaseA register fixes.
//   - __launch_bounds__(256,2): license high VGPR so the 64 Q-fragment
//     registers stay resident (R6's VGPR=72 showed the compiler was
//     reloading them in-loop -> latency-bound, MfmaUtil 28%).
//   - copy-free unroll-2 double buffer (even/odd register sets; loads for
//     step st+2 issued right after step st consumes its buffer).
//   - per-tile dependency split: acc_hi (4-chain) + acc_lo (2-chain).
// Phase B / filter math unchanged from R6 (EPS=0.05, 3-term split certified
// key error <= ~0.014; C~1 rescore blocks/query).

#define NTOT   16384
#define DIM    64
#define SBLK   256                // bmin granularity
#define NSB    (NTOT / SBLK)      // 64
#define EPS    0.05f
#define FLT_BIG 3.4e38f

typedef __attribute__((ext_vector_type(8))) short short8;
typedef __attribute__((ext_vector_type(4))) float float4v;

__device__ __forceinline__ ushort bf16_rne(float x) {
  unsigned u = __float_as_uint(x);
  return (ushort)((u + 0x7FFF + ((u >> 16) & 1)) >> 16);
}

// ---------------------------------------------------------------------------
__global__ __launch_bounds__(256) void k_split(
    const float* __restrict__ S, const float* __restrict__ Q,
    ushort* __restrict__ Sh, ushort* __restrict__ Sl,
    ushort* __restrict__ Qh, ushort* __restrict__ Ql) {
  const int t = blockIdx.x * 256 + threadIdx.x;  // 32768 rows x 16 float4
  const int row = t >> 4;
  const int c4 = (t & 15) << 2;
  const bool isS = row < NTOT;
  const int r = isS ? row : row - NTOT;
  const float4 v = *(const float4*)&(isS ? S : Q)[(size_t)r * DIM + c4];
  const float f[4] = {v.x, v.y, v.z, v.w};
  ushort h[4], l[4];
#pragma unroll
  for (int i = 0; i < 4; ++i) {
    h[i] = bf16_rne(f[i]);
    const float hf = __uint_as_float(((unsigned)h[i]) << 16);
    l[i] = bf16_rne(f[i] - hf);
  }
  *(ushort4*)&(isS ? Sh : Qh)[(size_t)r * DIM + c4] =
      make_ushort4(h[0], h[1], h[2], h[3]);
  *(ushort4*)&(isS ? Sl : Ql)[(size_t)r * DIM + c4] =
      make_ushort4(l[0], l[1], l[2], l[3]);
}

// ---------------------------------------------------------------------------
__global__ __launch_bounds__(256) void k_rowsq(
    const float* __restrict__ in, float* __restrict__ sq) {
  const int r = blockIdx.x * 256 + threadIdx.x;
  const float4* row = (const float4*)(in + (size_t)r * DIM);
  float s = 0.0f;
#pragma unroll
  for (int j = 0; j < 16; ++j) {
    const float4 v = row[j];
    s = fmaf(v.x, v.x, s);
    s = fmaf(v.y, v.y, s);
    s = fmaf(v.z, v.z, s);
    s = fmaf(v.w, v.w, s);
  }
  sq[r] = s;
}

// ---------------------------------------------------------------------------
// Transpose [nrows][64] -> [64][nrows]. Runs AFTER phase A (S_T aliases
// Sh/Sl storage).
__global__ __launch_bounds__(256) void k_transpose(
    const float* __restrict__ in, float* __restrict__ outT) {
  __shared__ float tile[64][65];
  const int tx = threadIdx.x & 63;
  const int ty = threadIdx.x >> 6;
  const int rbase = blockIdx.x * 64;
#pragma unroll
  for (int i = 0; i < 16; ++i) {
    const int r = i * 4 + ty;
    tile[r][tx] = in[(rbase + r) * DIM + tx];
  }
  __syncthreads();
#pragma unroll
  for (int i = 0; i < 16; ++i) {
    const int d = i * 4 + ty;
    outT[d * NTOT + rbase + tx] = tile[tx][d];
  }
}

// ---------------------------------------------------------------------------
// Phase A: block = 4 waves; wave w: 64 queries x 512 supports.
// grid = (NTOT/64, 8). A = supports (M), B = queries (N), 16x16x32 bf16.
// A frag: lane l holds A[m=l&15][k=(l>>4)*8+j]; B frag: B[k][n=l&15]=Q[n][k];
// C/D: col(n)=l&15, row(m)=(l>>4)*4+reg.  (Layouts HW-verified R4-R6.)

#define MFMA16(A, B, C) __builtin_amdgcn_mfma_f32_16x16x32_bf16(A, B, C, 0, 0, 0)

// One 16-support step: 24 MFMA (4 tiles x (4-chain hi + 2-chain lo)),
// epilogue folds into running block-min.
#define STEP_COMPUTE(H0, H1, L0, L1, SQ)                                   \
  do {                                                                     \
    _Pragma("unroll")                                                      \
    for (int t = 0; t < 4; ++t) {                                          \
      float4v ah = {0.f, 0.f, 0.f, 0.f};                                   \
      float4v al = {0.f, 0.f, 0.f, 0.f};                                   \
      ah = MFMA16(H0, qh[t][0], ah);                                       \
      al = MFMA16(H0, qlo[t][0], al);                                      \
      ah = MFMA16(H1, qh[t][1], ah);                                       \
      al = MFMA16(H1, qlo[t][1], al);                                      \
      ah = MFMA16(L0, qh[t][0], ah);                                       \
      ah = MFMA16(L1, qh[t][1], ah);                                       \
      const float k0 = fmaf(-2.f, ah[0], fmaf(-2.f, al[0], SQ.x));         \
      const float k1 = fmaf(-2.f, ah[1], fmaf(-2.f, al[1], SQ.y));         \
      const float k2 = fmaf(-2.f, ah[2], fmaf(-2.f, al[2], SQ.z));         \
      const float k3 = fmaf(-2.f, ah[3], fmaf(-2.f, al[3], SQ.w));         \
      bmr[t] = fminf(bmr[t], fminf(fminf(k0, k1), fminf(k2, k3)));         \
    }                                                                      \
  } while (0)

__global__ __launch_bounds__(256, 2) void k_phaseA(
    const ushort* __restrict__ Sh, const ushort* __restrict__ Sl,
    const ushort* __restrict__ Qh, const ushort* __restrict__ Ql,
    const float* __restrict__ sqS, float* __restrict__ bmin) {
  const int tid = threadIdx.x;
  const int l = tid & 63;
  const int w = tid >> 6;
  const int lm = l & 15;
  const int lq = l >> 4;
  const int qbase = blockIdx.x * 64;
  const int sbase = blockIdx.y * 2048 + w * 512;

  // Query (B) fragments, hi and lo: 4 tiles x 2 k-chunks. 64 VGPRs, live
  // across the whole loop (launch_bounds(256,2) licenses the pressure).
  short8 qh[4][2], qlo[4][2];
#pragma unroll
  for (int t = 0; t < 4; ++t) {
    const size_t rq = (size_t)(qbase + t * 16 + lm) * DIM + lq * 8;
    qh[t][0] = *(const short8*)&Qh[rq];
    qh[t][1] = *(const short8*)&Qh[rq + 32];
    qlo[t][0] = *(const short8*)&Ql[rq];
    qlo[t][1] = *(const short8*)&Ql[rq + 32];
  }

  const ushort* pSh = Sh + (size_t)(sbase + lm) * DIM + lq * 8;
  const ushort* pSl = Sl + (size_t)(sbase + lm) * DIM + lq * 8;
  const float* psq = sqS + sbase + lq * 4;

  // Copy-free double buffer: even steps use (a), odd steps use (b).
  short8 h0a = *(const short8*)(pSh);
  short8 h1a = *(const short8*)(pSh + 32);
  short8 l0a = *(const short8*)(pSl);
  short8 l1a = *(const short8*)(pSl + 32);
  float4 sqa = *(const float4*)(psq);
  short8 h0b = *(const short8*)(pSh + 1024);
  short8 h1b = *(const short8*)(pSh + 1024 + 32);
  short8 l0b = *(const short8*)(pSl + 1024);
  short8 l1b = *(const short8*)(pSl + 1024 + 32);
  float4 sqb = *(const float4*)(psq + 16);

  float bmr[4] = {FLT_BIG, FLT_BIG, FLT_BIG, FLT_BIG};

  for (int st = 0; st < 32; st += 2) {
    // Even step (buffers a); then refill a for step st+2.
    STEP_COMPUTE(h0a, h1a, l0a, l1a, sqa);
    if (st + 2 < 32) {
      const int off = (st + 2) * 1024;  // 16 rows x 64 ushort
      h0a = *(const short8*)(pSh + off);
      h1a = *(const short8*)(pSh + off + 32);
      l0a = *(const short8*)(pSl + off);
      l1a = *(const short8*)(pSl + off + 32);
      sqa = *(const float4*)(psq + (st + 2) * 16);
    }
    // Odd step st+1 (buffers b); then refill b for step st+3.
    STEP_COMPUTE(h0b, h1b, l0b, l1b, sqb);
    if (st + 3 < 32) {
      const int off = (st + 3) * 1024;
      h0b = *(const short8*)(pSh + off);
      h1b = *(const short8*)(pSh + off + 32);
      l0b = *(const short8*)(pSl + off);
      l1b = *(const short8*)(pSl + off + 32);
      sqb = *(const float4*)(psq + (st + 3) * 16);
    }
    if (((st + 1) & 15) == 15) {  // finished a 256-support block (s=15,31)
      const int gb = blockIdx.y * 8 + w * 2 + ((st + 1) >> 4);
#pragma unroll
      for (int t = 0; t < 4; ++t) {
        float v = bmr[t];
        v = fminf(v, __shfl_xor(v, 16, 64));
        v = fminf(v, __shfl_xor(v, 32, 64));
        if (lq == 0) bmin[(size_t)(qbase + t * 16 + lm) * NSB + gb] = v;
        bmr[t] = FLT_BIG;
      }
    }
  }
}

// ---------------------------------------------------------------------------
// Phase B: one wave per query; coalesced rescore from S_T. (Unchanged R6.)
__global__ __launch_bounds__(256) void k_phaseB(
    const float* __restrict__ S_T,   // [64][NTOT]
    const float* __restrict__ Q,     // [NTOT][64]
    const float* __restrict__ sqS, const float* __restrict__ bmin,
    const float* __restrict__ onehot, float* __restrict__ out) {
  __shared__ float sQrow[4][64];
  const int lane = threadIdx.x & 63;
  const int w = threadIdx.x >> 6;
  const int q = blockIdx.x * 4 + w;

  if (lane < 16)
    *(float4*)&sQrow[w][lane * 4] = *(const float4*)&Q[(size_t)q * DIM + lane * 4];
  __syncthreads();

  const float bv = bmin[(size_t)q * NSB + lane];  // lane <-> block
  float m = bv;
#pragma unroll
  for (int d = 1; d < 64; d <<= 1) m = fminf(m, __shfl_xor(m, d, 64));
  unsigned long long msk = __ballot(bv <= m + EPS);

  float bk = FLT_BIG;
  int bi = 0;
  while (msk) {  // ascending block order; wave-uniform control
    const int b = __ffsll((long long)msk) - 1;
    msk &= msk - 1;
    const int s0 = b * SBLK + lane * 4;  // 4 consecutive supports per lane
    float a0 = 0.f, a1 = 0.f, a2 = 0.f, a3 = 0.f;
#pragma unroll
    for (int c = 0; c < 16; ++c) {
      const float4 qv = *(const float4*)&sQrow[w][c * 4];  // LDS broadcast
      const float4 s0v = *(const float4*)&S_T[(size_t)(c * 4 + 0) * NTOT + s0];
      const float4 s1v = *(const float4*)&S_T[(size_t)(c * 4 + 1) * NTOT + s0];
      const float4 s2v = *(const float4*)&S_T[(size_t)(c * 4 + 2) * NTOT + s0];
      const float4 s3v = *(const float4*)&S_T[(size_t)(c * 4 + 3) * NTOT + s0];
      a0 = fmaf(qv.x, s0v.x, a0); a1 = fmaf(qv.x, s0v.y, a1);
      a2 = fmaf(qv.x, s0v.z, a2); a3 = fmaf(qv.x, s0v.w, a3);
      a0 = fmaf(qv.y, s1v.x, a0); a1 = fmaf(qv.y, s1v.y, a1);
      a2 = fmaf(qv.y, s1v.z, a2); a3 = fmaf(qv.y, s1v.w, a3);
      a0 = fmaf(qv.z, s2v.x, a0); a1 = fmaf(qv.z, s2v.y, a1);
      a2 = fmaf(qv.z, s2v.z, a2); a3 = fmaf(qv.z, s2v.w, a3);
      a0 = fmaf(qv.w, s3v.x, a0); a1 = fmaf(qv.w, s3v.y, a1);
      a2 = fmaf(qv.w, s3v.z, a2); a3 = fmaf(qv.w, s3v.w, a3);
    }
    const float4 sq4 = *(const float4*)&sqS[s0];
    const float k0 = fmaf(-2.f, a0, sq4.x);
    const float k1 = fmaf(-2.f, a1, sq4.y);
    const float k2 = fmaf(-2.f, a2, sq4.z);
    const float k3 = fmaf(-2.f, a3, sq4.w);
    bool u;  // ascending index, strict < => first minimum per lane
    u = k0 < bk; bk = u ? k0 : bk; bi = u ? s0 : bi;
    u = k1 < bk; bk = u ? k1 : bk; bi = u ? (s0 + 1) : bi;
    u = k2 < bk; bk = u ? k2 : bk; bi = u ? (s0 + 2) : bi;
    u = k3 < bk; bk = u ? k3 : bk; bi = u ? (s0 + 3) : bi;
  }
  // Cross-lane lexicographic argmin on exact keys => first-index semantics.
#pragma unroll
  for (int d = 1; d < 64; d <<= 1) {
    const float ok = __shfl_xor(bk, d, 64);
    const int oi = __shfl_xor(bi, d, 64);
    const bool u = (ok < bk) || (ok == bk && oi < bi);
    bk = u ? ok : bk;
    bi = u ? oi : bi;
  }
  // Label: one-hot rows exact {0,1}; first 1 == np.argmax.
  const float ov = onehot[(size_t)bi * 64 + lane];
  const unsigned long long lmask = __ballot(ov > 0.5f);
  const int label = __ffsll((long long)lmask) - 1;
  out[(size_t)q * 64 + lane] = (lane == label) ? 1.0f : 0.0f;
}

// ---------------------------------------------------------------------------
extern "C" void kernel_launch(void* const* d_in, const int* in_sizes, int n_in,
                              void* d_out, int out_size, void* d_ws, size_t ws_size,
                              hipStream_t stream) {
  const float* S = (const float*)d_in[0];   // [16384][64]
  const float* Q = (const float*)d_in[1];   // [16384][64]
  const float* OH = (const float*)d_in[2];  // [16384][64]
  float* out = (float*)d_out;

  char* ws = (char*)d_ws;
  ushort* Sh = (ushort*)ws;                                  // [0,2MB)
  ushort* Sl = (ushort*)(ws + (2u << 20));                   // [2,4MB)
  ushort* Qh = (ushort*)(ws + (4u << 20));                   // [4,6MB)
  ushort* Ql = (ushort*)(ws + (6u << 20));                   // [6,8MB)
  float* S_T = (float*)ws;                                   // aliases Sh+Sl
  float* sqS = (float*)(ws + (8u << 20));                    // 64 KB
  float* bmin = (float*)(ws + (8u << 20) + (64u << 10));     // 4 MB

  k_split<<<dim3(2048), 256, 0, stream>>>(S, Q, Sh, Sl, Qh, Ql);
  k_rowsq<<<dim3(NTOT / 256), 256, 0, stream>>>(S, sqS);
  k_phaseA<<<dim3(NTOT / 64, 8), 256, 0, stream>>>(Sh, Sl, Qh, Ql, sqS, bmin);
  k_transpose<<<dim3(NTOT / 64), 256, 0, stream>>>(S, S_T);  // after phaseA
  k_phaseB<<<dim3(NTOT / 4), 256, 0, stream>>>(S_T, Q, sqS, bmin, OH, out);
  (void)in_sizes; (void)n_in; (void)out_size; (void)ws_size;
}

// Round 8
// 198.073 us; speedup vs baseline: 1.3054x; 1.3054x over previous
//
#include <hip/hip_runtime.h>

// KNN argmin over L2, round 8: MFMA-panel-swizzled operand storage.
// R6/R7 both pinned at 157us with MfmaUtil 27% regardless of VGPR/ILP
// changes -> phase A is TA/transaction-bound: fragment loads from row-major
// Sh/Sl scatter 64 lanes over 16 rows x 128B stride (~24 lines/instr).
// Fix: k_split stores bf16 hi/lo arrays directly in MFMA fragment lane
// order per 16-row panel:
//   off(r,k) = (r>>4)*1024 + (k>=32)*512 + (((k&31)>>3)*16 + (r&15))*8 + (k&7)
// so phase A (and its Q-frag setup) loads are lane-contiguous 1KB wave
// loads. Phase A math/tiling unchanged from R7; grid swapped to
// (split, qtile) so block%8 ~ XCD gets one 512KB S-slice (L2-resident).
//
// Filter math unchanged (3-term split, certified key err <= ~0.014,
// EPS=0.05): rescore set provably contains the true first argmin.
// Phase B exact fp32, strict-< ascending + lex cross-lane => np.argmin
// first-index semantics. (Unchanged from R6/R7.)

#define NTOT   16384
#define DIM    64
#define SBLK   256                // bmin granularity
#define NSB    (NTOT / SBLK)      // 64
#define EPS    0.05f
#define FLT_BIG 3.4e38f

typedef __attribute__((ext_vector_type(8))) short short8;
typedef __attribute__((ext_vector_type(4))) float float4v;

__device__ __forceinline__ ushort bf16_rne(float x) {
  unsigned u = __float_as_uint(x);
  return (ushort)((u + 0x7FFF + ((u >> 16) & 1)) >> 16);
}

// ---------------------------------------------------------------------------
// Split S and Q into (hi, lo) bf16 arrays stored in MFMA panel order.
__global__ __launch_bounds__(256) void k_split(
    const float* __restrict__ S, const float* __restrict__ Q,
    ushort* __restrict__ Sh, ushort* __restrict__ Sl,
    ushort* __restrict__ Qh, ushort* __restrict__ Ql) {
  const int t = blockIdx.x * 256 + threadIdx.x;  // 32768 rows x 16 float4
  const int row = t >> 4;
  const int c4 = (t & 15) << 2;                  // k base of this float4
  const bool isS = row < NTOT;
  const int r = isS ? row : row - NTOT;
  const float4 v = *(const float4*)&(isS ? S : Q)[(size_t)r * DIM + c4];
  const float f[4] = {v.x, v.y, v.z, v.w};
  ushort h[4], l[4];
#pragma unroll
  for (int i = 0; i < 4; ++i) {
    h[i] = bf16_rne(f[i]);
    const float hf = __uint_as_float(((unsigned)h[i]) << 16);
    l[i] = bf16_rne(f[i] - hf);
  }
  // Panel-swizzled offset (4 contiguous ushorts: c4&7 in {0,4}).
  const int off = (r >> 4) * 1024 + (c4 >> 5) * 512 +
                  (((c4 & 31) >> 3) * 16 + (r & 15)) * 8 + (c4 & 7);
  *(ushort4*)&(isS ? Sh : Qh)[off] = make_ushort4(h[0], h[1], h[2], h[3]);
  *(ushort4*)&(isS ? Sl : Ql)[off] = make_ushort4(l[0], l[1], l[2], l[3]);
}

// ---------------------------------------------------------------------------
__global__ __launch_bounds__(256) void k_rowsq(
    const float* __restrict__ in, float* __restrict__ sq) {
  const int r = blockIdx.x * 256 + threadIdx.x;
  const float4* row = (const float4*)(in + (size_t)r * DIM);
  float s = 0.0f;
#pragma unroll
  for (int j = 0; j < 16; ++j) {
    const float4 v = row[j];
    s = fmaf(v.x, v.x, s);
    s = fmaf(v.y, v.y, s);
    s = fmaf(v.z, v.z, s);
    s = fmaf(v.w, v.w, s);
  }
  sq[r] = s;
}

// ---------------------------------------------------------------------------
// Transpose [nrows][64] -> [64][nrows]. Runs AFTER phase A (S_T aliases
// Sh/Sl storage).
__global__ __launch_bounds__(256) void k_transpose(
    const float* __restrict__ in, float* __restrict__ outT) {
  __shared__ float tile[64][65];
  const int tx = threadIdx.x & 63;
  const int ty = threadIdx.x >> 6;
  const int rbase = blockIdx.x * 64;
#pragma unroll
  for (int i = 0; i < 16; ++i) {
    const int r = i * 4 + ty;
    tile[r][tx] = in[(rbase + r) * DIM + tx];
  }
  __syncthreads();
#pragma unroll
  for (int i = 0; i < 16; ++i) {
    const int d = i * 4 + ty;
    outT[d * NTOT + rbase + tx] = tile[tx][d];
  }
}

// ---------------------------------------------------------------------------
// Phase A: block = 4 waves; wave w: 64 queries x 512 supports.
// grid = (8 splits, 256 q-tiles) -> block%8 ~ XCD sees one S-slice.
// All fragment loads are lane-contiguous (panel-swizzled storage):
//   frag addr = panel_base + half*512 + lane*8   (1KB contiguous per wave).
// MFMA layouts as HW-verified R4-R7.

#define MFMA16(A, B, C) __builtin_amdgcn_mfma_f32_16x16x32_bf16(A, B, C, 0, 0, 0)

#define STEP_COMPUTE(H0, H1, L0, L1, SQ)                                   \
  do {                                                                     \
    _Pragma("unroll")                                                      \
    for (int t = 0; t < 4; ++t) {                                          \
      float4v ah = {0.f, 0.f, 0.f, 0.f};                                   \
      float4v al = {0.f, 0.f, 0.f, 0.f};                                   \
      ah = MFMA16(H0, qh[t][0], ah);                                       \
      al = MFMA16(H0, qlo[t][0], al);                                      \
      ah = MFMA16(H1, qh[t][1], ah);                                       \
      al = MFMA16(H1, qlo[t][1], al);                                      \
      ah = MFMA16(L0, qh[t][0], ah);                                       \
      ah = MFMA16(L1, qh[t][1], ah);                                       \
      const float k0 = fmaf(-2.f, ah[0], fmaf(-2.f, al[0], SQ.x));         \
      const float k1 = fmaf(-2.f, ah[1], fmaf(-2.f, al[1], SQ.y));         \
      const float k2 = fmaf(-2.f, ah[2], fmaf(-2.f, al[2], SQ.z));         \
      const float k3 = fmaf(-2.f, ah[3], fmaf(-2.f, al[3], SQ.w));         \
      bmr[t] = fminf(bmr[t], fminf(fminf(k0, k1), fminf(k2, k3)));         \
    }                                                                      \
  } while (0)

__global__ __launch_bounds__(256, 2) void k_phaseA(
    const ushort* __restrict__ Sh, const ushort* __restrict__ Sl,
    const ushort* __restrict__ Qh, const ushort* __restrict__ Ql,
    const float* __restrict__ sqS, float* __restrict__ bmin) {
  const int tid = threadIdx.x;
  const int l = tid & 63;
  const int w = tid >> 6;
  const int lm = l & 15;
  const int lq = l >> 4;
  const int split = blockIdx.x;       // 0..7
  const int qbase = blockIdx.y * 64;  // 0..16320
  const int sbase = split * 2048 + w * 512;

  // Query (B) fragments, hi and lo: 4 tiles x 2 k-chunks. Lane-contiguous.
  short8 qh[4][2], qlo[4][2];
#pragma unroll
  for (int t = 0; t < 4; ++t) {
    const size_t pb = (size_t)((qbase >> 4) + t) * 1024 + (size_t)l * 8;
    qh[t][0] = *(const short8*)&Qh[pb];
    qh[t][1] = *(const short8*)&Qh[pb + 512];
    qlo[t][0] = *(const short8*)&Ql[pb];
    qlo[t][1] = *(const short8*)&Ql[pb + 512];
  }

  // Support panel pointers: panel for step st at base + st*1024.
  const ushort* pSh = Sh + (size_t)(sbase >> 4) * 1024 + (size_t)l * 8;
  const ushort* pSl = Sl + (size_t)(sbase >> 4) * 1024 + (size_t)l * 8;
  const float* psq = sqS + sbase + lq * 4;

  // Copy-free double buffer: even steps use (a), odd steps use (b).
  short8 h0a = *(const short8*)(pSh);
  short8 h1a = *(const short8*)(pSh + 512);
  short8 l0a = *(const short8*)(pSl);
  short8 l1a = *(const short8*)(pSl + 512);
  float4 sqa = *(const float4*)(psq);
  short8 h0b = *(const short8*)(pSh + 1024);
  short8 h1b = *(const short8*)(pSh + 1024 + 512);
  short8 l0b = *(const short8*)(pSl + 1024);
  short8 l1b = *(const short8*)(pSl + 1024 + 512);
  float4 sqb = *(const float4*)(psq + 16);

  float bmr[4] = {FLT_BIG, FLT_BIG, FLT_BIG, FLT_BIG};

  for (int st = 0; st < 32; st += 2) {
    STEP_COMPUTE(h0a, h1a, l0a, l1a, sqa);
    if (st + 2 < 32) {
      const int off = (st + 2) * 1024;
      h0a = *(const short8*)(pSh + off);
      h1a = *(const short8*)(pSh + off + 512);
      l0a = *(const short8*)(pSl + off);
      l1a = *(const short8*)(pSl + off + 512);
      sqa = *(const float4*)(psq + (st + 2) * 16);
    }
    STEP_COMPUTE(h0b, h1b, l0b, l1b, sqb);
    if (st + 3 < 32) {
      const int off = (st + 3) * 1024;
      h0b = *(const short8*)(pSh + off);
      h1b = *(const short8*)(pSh + off + 512);
      l0b = *(const short8*)(pSl + off);
      l1b = *(const short8*)(pSl + off + 512);
      sqb = *(const float4*)(psq + (st + 3) * 16);
    }
    if (((st + 1) & 15) == 15) {  // finished a 256-support block
      const int gb = split * 8 + w * 2 + ((st + 1) >> 4);
#pragma unroll
      for (int t = 0; t < 4; ++t) {
        float v = bmr[t];
        v = fminf(v, __shfl_xor(v, 16, 64));
        v = fminf(v, __shfl_xor(v, 32, 64));
        if (lq == 0) bmin[(size_t)(qbase + t * 16 + lm) * NSB + gb] = v;
        bmr[t] = FLT_BIG;
      }
    }
  }
}

// ---------------------------------------------------------------------------
// Phase B: one wave per query; coalesced rescore from S_T. (Unchanged.)
__global__ __launch_bounds__(256) void k_phaseB(
    const float* __restrict__ S_T,   // [64][NTOT]
    const float* __restrict__ Q,     // [NTOT][64]
    const float* __restrict__ sqS, const float* __restrict__ bmin,
    const float* __restrict__ onehot, float* __restrict__ out) {
  __shared__ float sQrow[4][64];
  const int lane = threadIdx.x & 63;
  const int w = threadIdx.x >> 6;
  const int q = blockIdx.x * 4 + w;

  if (lane < 16)
    *(float4*)&sQrow[w][lane * 4] = *(const float4*)&Q[(size_t)q * DIM + lane * 4];
  __syncthreads();

  const float bv = bmin[(size_t)q * NSB + lane];  // lane <-> block
  float m = bv;
#pragma unroll
  for (int d = 1; d < 64; d <<= 1) m = fminf(m, __shfl_xor(m, d, 64));
  unsigned long long msk = __ballot(bv <= m + EPS);

  float bk = FLT_BIG;
  int bi = 0;
  while (msk) {  // ascending block order; wave-uniform control
    const int b = __ffsll((long long)msk) - 1;
    msk &= msk - 1;
    const int s0 = b * SBLK + lane * 4;  // 4 consecutive supports per lane
    float a0 = 0.f, a1 = 0.f, a2 = 0.f, a3 = 0.f;
#pragma unroll
    for (int c = 0; c < 16; ++c) {
      const float4 qv = *(const float4*)&sQrow[w][c * 4];  // LDS broadcast
      const float4 s0v = *(const float4*)&S_T[(size_t)(c * 4 + 0) * NTOT + s0];
      const float4 s1v = *(const float4*)&S_T[(size_t)(c * 4 + 1) * NTOT + s0];
      const float4 s2v = *(const float4*)&S_T[(size_t)(c * 4 + 2) * NTOT + s0];
      const float4 s3v = *(const float4*)&S_T[(size_t)(c * 4 + 3) * NTOT + s0];
      a0 = fmaf(qv.x, s0v.x, a0); a1 = fmaf(qv.x, s0v.y, a1);
      a2 = fmaf(qv.x, s0v.z, a2); a3 = fmaf(qv.x, s0v.w, a3);
      a0 = fmaf(qv.y, s1v.x, a0); a1 = fmaf(qv.y, s1v.y, a1);
      a2 = fmaf(qv.y, s1v.z, a2); a3 = fmaf(qv.y, s1v.w, a3);
      a0 = fmaf(qv.z, s2v.x, a0); a1 = fmaf(qv.z, s2v.y, a1);
      a2 = fmaf(qv.z, s2v.z, a2); a3 = fmaf(qv.z, s2v.w, a3);
      a0 = fmaf(qv.w, s3v.x, a0); a1 = fmaf(qv.w, s3v.y, a1);
      a2 = fmaf(qv.w, s3v.z, a2); a3 = fmaf(qv.w, s3v.w, a3);
    }
    const float4 sq4 = *(const float4*)&sqS[s0];
    const float k0 = fmaf(-2.f, a0, sq4.x);
    const float k1 = fmaf(-2.f, a1, sq4.y);
    const float k2 = fmaf(-2.f, a2, sq4.z);
    const float k3 = fmaf(-2.f, a3, sq4.w);
    bool u;  // ascending index, strict < => first minimum per lane
    u = k0 < bk; bk = u ? k0 : bk; bi = u ? s0 : bi;
    u = k1 < bk; bk = u ? k1 : bk; bi = u ? (s0 + 1) : bi;
    u = k2 < bk; bk = u ? k2 : bk; bi = u ? (s0 + 2) : bi;
    u = k3 < bk; bk = u ? k3 : bk; bi = u ? (s0 + 3) : bi;
  }
  // Cross-lane lexicographic argmin on exact keys => first-index semantics.
#pragma unroll
  for (int d = 1; d < 64; d <<= 1) {
    const float ok = __shfl_xor(bk, d, 64);
    const int oi = __shfl_xor(bi, d, 64);
    const bool u = (ok < bk) || (ok == bk && oi < bi);
    bk = u ? ok : bk;
    bi = u ? oi : bi;
  }
  // Label: one-hot rows exact {0,1}; first 1 == np.argmax.
  const float ov = onehot[(size_t)bi * 64 + lane];
  const unsigned long long lmask = __ballot(ov > 0.5f);
  const int label = __ffsll((long long)lmask) - 1;
  out[(size_t)q * 64 + lane] = (lane == label) ? 1.0f : 0.0f;
}

// ---------------------------------------------------------------------------
extern "C" void kernel_launch(void* const* d_in, const int* in_sizes, int n_in,
                              void* d_out, int out_size, void* d_ws, size_t ws_size,
                              hipStream_t stream) {
  const float* S = (const float*)d_in[0];   // [16384][64]
  const float* Q = (const float*)d_in[1];   // [16384][64]
  const float* OH = (const float*)d_in[2];  // [16384][64]
  float* out = (float*)d_out;

  char* ws = (char*)d_ws;
  ushort* Sh = (ushort*)ws;                                  // [0,2MB)
  ushort* Sl = (ushort*)(ws + (2u << 20));                   // [2,4MB)
  ushort* Qh = (ushort*)(ws + (4u << 20));                   // [4,6MB)
  ushort* Ql = (ushort*)(ws + (6u << 20));                   // [6,8MB)
  float* S_T = (float*)ws;                                   // aliases Sh+Sl
  float* sqS = (float*)(ws + (8u << 20));                    // 64 KB
  float* bmin = (float*)(ws + (8u << 20) + (64u << 10));     // 4 MB

  k_split<<<dim3(2048), 256, 0, stream>>>(S, Q, Sh, Sl, Qh, Ql);
  k_rowsq<<<dim3(NTOT / 256), 256, 0, stream>>>(S, sqS);
  k_phaseA<<<dim3(8, NTOT / 64), 256, 0, stream>>>(Sh, Sl, Qh, Ql, sqS, bmin);
  k_transpose<<<dim3(NTOT / 64), 256, 0, stream>>>(S, S_T);  // after phaseA
  k_phaseB<<<dim3(NTOT / 4), 256, 0, stream>>>(S_T, Q, sqS, bmin, OH, out);
  (void)in_sizes; (void)n_in; (void)out_size; (void)ws_size;
}